// Round 8
// baseline (238.984 us; speedup 1.0000x reference)
//
#include <hip/hip_runtime.h>
#include <stdint.h>

#define HBINS 8192
#define HSHIFT 19
#define HWORDS (HBINS / 2)
#define CAND 2048
#define NSLICES 16
#define HTHREADS 256
#define CTHREADS 256
#define STHREADS 1024

typedef unsigned int u32;
typedef unsigned long long u64;

// order-preserving float->uint map (ascending uint == ascending float)
__device__ __forceinline__ u32 f2s(float f) {
  u32 b = __float_as_uint(f);
  return b ^ ((b & 0x80000000u) ? 0xFFFFFFFFu : 0x80000000u);
}
__device__ __forceinline__ float s2f(u32 s) {
  u32 b = (s & 0x80000000u) ? (s ^ 0x80000000u) : ~s;
  return __uint_as_float(b);
}
__device__ __forceinline__ u32 rotl32(u32 x, int r) { return (x << r) | (x >> (32 - r)); }

__device__ __forceinline__ u64 shfl_xor_u64(u64 v, int mask) {
  int lo = __shfl_xor((int)(u32)v, mask, 64);
  int hi = __shfl_xor((int)(u32)(v >> 32), mask, 64);
  return ((u64)(u32)hi << 32) | (u32)lo;
}

// JAX threefry2x32, partitionable counter mode, key = jax.random.key(42) -> (0,42).
__device__ __forceinline__ u32 threefry_bits(u32 ctr) {
  const u32 ks0 = 0u, ks1 = 42u, ks2 = 0x1BD11BDAu ^ 0u ^ 42u;
  u32 x0 = ks0;
  u32 x1 = ctr + ks1;
#define TFR(r) { x0 += x1; x1 = rotl32(x1, (r)); x1 ^= x0; }
  TFR(13) TFR(15) TFR(26) TFR(6)   x0 += ks1; x1 += ks2 + 1u;
  TFR(17) TFR(29) TFR(16) TFR(24)  x0 += ks2; x1 += ks0 + 2u;
  TFR(13) TFR(15) TFR(26) TFR(6)   x0 += ks0; x1 += ks1 + 3u;
  TFR(17) TFR(29) TFR(16) TFR(24)  x0 += ks1; x1 += ks2 + 4u;
  TFR(13) TFR(15) TFR(26) TFR(6)   x0 += ks2; x1 += ks0 + 5u;
#undef TFR
  return x0 ^ x1;
}

// ---------------- fused per-slice histogram + last-block inline select -------
// Histogram: 8192 bins, single-copy packed u16 pairs in 16 KB LDS (per-slice
// count <= 8000 < 2^16, no cross-field carry) -> 8 blocks/CU.
// Completion: per-row done counter; __threadfence() (agent-scope) provides the
// release/acquire ordering around it. The last slice block for a row runs
// selection inline (parallel suffix-scan, no serial tid0 chain).
__global__ __launch_bounds__(HTHREADS)
void histsel_kernel(const float* __restrict__ logits, u32* __restrict__ ghist,
                    u32* __restrict__ done, const int* __restrict__ topks,
                    u32* __restrict__ gthr, u32* __restrict__ gcs,
                    u32* __restrict__ gcount, int V, int slice_len) {
  const int row = blockIdx.x / NSLICES;
  const int sl  = blockIdx.x % NSLICES;
  const int tid = threadIdx.x;
  __shared__ u32 hp[HWORDS];        // 16 KB: hist (packed u16) then select scratch
  __shared__ u32 part[HTHREADS];    // suffix partials (16 bins each)
  __shared__ int sh_last, sh_pstar;

  for (int i = tid; i < HWORDS; i += HTHREADS) hp[i] = 0u;
  __syncthreads();

  int rem = V - sl * slice_len;
  if (rem > slice_len) rem = slice_len;
  if (rem < 0) rem = 0;
  const float* src = logits + (size_t)row * (size_t)V + (size_t)sl * slice_len;
  const int n4 = rem >> 2;
  const float4* p4 = (const float4*)src;
  for (int i = tid; i < n4; i += HTHREADS) {
    float4 w = p4[i];
    u32 b0 = f2s(w.x) >> HSHIFT;
    u32 b1 = f2s(w.y) >> HSHIFT;
    u32 b2 = f2s(w.z) >> HSHIFT;
    u32 b3 = f2s(w.w) >> HSHIFT;
    atomicAdd(&hp[b0 >> 1], 1u << ((b0 & 1u) << 4));
    atomicAdd(&hp[b1 >> 1], 1u << ((b1 & 1u) << 4));
    atomicAdd(&hp[b2 >> 1], 1u << ((b2 & 1u) << 4));
    atomicAdd(&hp[b3 >> 1], 1u << ((b3 & 1u) << 4));
  }
  for (int i = (n4 << 2) + tid; i < rem; i += HTHREADS) {
    u32 b = f2s(src[i]) >> HSHIFT;
    atomicAdd(&hp[b >> 1], 1u << ((b & 1u) << 4));
  }
  __syncthreads();

  u32* gh = ghist + (size_t)row * HBINS;
  for (int p = tid; p < HWORDS; p += HTHREADS) {
    u32 s = hp[p];
    if (s) {
      u32 lo = s & 0xFFFFu;
      u32 hi = s >> 16;
      if (lo) atomicAdd(&gh[2 * p], lo);       // sparse merge
      if (hi) atomicAdd(&gh[2 * p + 1], hi);
    }
  }
  __syncthreads();   // all merges of this block issued

  if (tid == 0) {
    __threadfence();   // release: merges visible agent-wide before done++
    u32 old = atomicAdd(&done[row], 1u);
    sh_last = (old == (u32)(NSLICES - 1));
  }
  __syncthreads();
  if (!sh_last) return;

  // ---- last block for this row: inline select ----
  __threadfence();     // acquire: observe all rows' merges before reading ghist
  int k = topks[row];
  if (k < 1) k = 1;
  if (k > V) k = V;
  const u32 ku = (u32)k;

  u32 base = 0;
  for (int h = 1; h >= 0; --h) {     // halves, top (high bins) first
    __syncthreads();
    for (int i = tid; i < 4096; i += HTHREADS)
      hp[i] = __hip_atomic_load(&gh[h * 4096 + i], __ATOMIC_RELAXED,
                                __HIP_MEMORY_SCOPE_AGENT);
    __syncthreads();
    {
      u32 s = 0;
      for (int j = 0; j < 16; ++j) s += hp[tid * 16 + j];
      part[tid] = s;
    }
    __syncthreads();
    // Hillis-Steele suffix scan: part[t] = sum_{q>=t} part[q]
    for (int st = 1; st < HTHREADS; st <<= 1) {
      u32 v = (tid + st < HTHREADS) ? part[tid + st] : 0u;
      __syncthreads();
      part[tid] += v;
      __syncthreads();
    }
    const u32 tot = part[0];
    if (base + tot >= ku) {
      // boundary in this half: pstar = max p with base+part[p] >= ku
      if (base + part[tid] >= ku &&
          (tid == HTHREADS - 1 || base + part[tid + 1] < ku))
        sh_pstar = tid;
      __syncthreads();
      const int pstar = sh_pstar;
      const u32 tail = base + ((pstar < HTHREADS - 1) ? part[pstar + 1] : 0u);
      if (tid < 16) {
        u32 sb = tail;                       // suffix count from bin (pstar*16+tid)
        for (int j = 15; j >= tid; --j) sb += hp[pstar * 16 + j];
        u32 sb_next = sb - hp[pstar * 16 + tid];
        if (sb >= ku && (tid == 15 || sb_next < ku)) {
          int bstar = h * 4096 + pstar * 16 + tid;
          gthr[row] = (u32)bstar << HSHIFT;
          gcs[row] = (sb < (u32)CAND) ? sb : (u32)CAND;
          gcount[row] = 0u;
        }
      }
      return;
    }
    base += tot;
  }
}

// ---------------- per-slice collect (full machine, no hist traffic) -----------
__global__ __launch_bounds__(CTHREADS)
void collect_kernel(const float* __restrict__ logits,
                    const float* __restrict__ temps,
                    const u32* __restrict__ gthr,
                    u32* __restrict__ gcount,
                    u64* __restrict__ gcand, int V, int slice_len) {
  const int row = blockIdx.x / NSLICES;
  const int sl  = blockIdx.x % NSLICES;
  const int tid = threadIdx.x;

  __shared__ u64 stage[CAND];
  __shared__ int sh_cnt, sh_base;
  if (tid == 0) sh_cnt = 0;
  __syncthreads();

  const u32 thr = gthr[row];
  const float t = temps[row];
  int rem = V - sl * slice_len;
  if (rem > slice_len) rem = slice_len;
  if (rem < 0) rem = 0;
  const float* src = logits + (size_t)row * (size_t)V + (size_t)sl * slice_len;
  const u32 ibase = (u32)(sl * slice_len);
  const int n4 = rem >> 2;
  const float4* p4 = (const float4*)src;
  for (int i = tid; i < n4; i += CTHREADS) {
    float4 w = p4[i];
    if (f2s(w.x) >= thr) { int pos = atomicAdd(&sh_cnt, 1); if (pos < CAND) stage[pos] = ((u64)f2s(w.x / t) << 32) | (ibase + 4u * i + 0u); }
    if (f2s(w.y) >= thr) { int pos = atomicAdd(&sh_cnt, 1); if (pos < CAND) stage[pos] = ((u64)f2s(w.y / t) << 32) | (ibase + 4u * i + 1u); }
    if (f2s(w.z) >= thr) { int pos = atomicAdd(&sh_cnt, 1); if (pos < CAND) stage[pos] = ((u64)f2s(w.z / t) << 32) | (ibase + 4u * i + 2u); }
    if (f2s(w.w) >= thr) { int pos = atomicAdd(&sh_cnt, 1); if (pos < CAND) stage[pos] = ((u64)f2s(w.w / t) << 32) | (ibase + 4u * i + 3u); }
  }
  for (int i = (n4 << 2) + tid; i < rem; i += CTHREADS) {
    float l = src[i];
    if (f2s(l) >= thr) { int pos = atomicAdd(&sh_cnt, 1); if (pos < CAND) stage[pos] = ((u64)f2s(l / t) << 32) | (ibase + (u32)i); }
  }
  __syncthreads();
  int n = sh_cnt;
  if (n > CAND) n = CAND;
  if (tid == 0) sh_base = (int)atomicAdd(&gcount[row], (u32)n);
  __syncthreads();
  const int base = sh_base;
  u64* gc = gcand + (size_t)row * CAND;
  for (int i = tid; i < n; i += CTHREADS) {
    int dst = base + i;
    if (dst < CAND) gc[dst] = stage[i];
  }
}

// ---------------- per-row: hybrid reg/LDS sort + softmax chain + gumbel -------
__global__ __launch_bounds__(STHREADS)
void Sampler_73529840107542_kernel(const float* __restrict__ minps,
                                   const float* __restrict__ topps,
                                   const int* __restrict__ topks,
                                   const u32* __restrict__ gcs,
                                   const u64* __restrict__ gcand,
                                   int* __restrict__ out, int V) {
  const int b = blockIdx.x;
  const int tid = threadIdx.x;
  const int w = tid >> 6;
  const int l = tid & 63;
  const float one_minus_p = 1.0f - topps[b];
  const float minp = minps[b];
  int k = topks[b];
  if (k < 1) k = 1;
  if (k > V) k = V;

  __shared__ __align__(16) unsigned char arena[34816];
  u64* cand   = (u64*)(arena);              // [0,16384)
  float* bufA = (float*)(arena + 16384);    // [16384,24576) e / p
  float* bufB = (float*)(arena + 24576);    // [24576,32768) cumsum
  unsigned char* keepf = arena + 32768;     // [32768,34816)
  u64* red64  = (u64*)(arena + 16384);      // aliases bufA (argmax stage)
  float* redA = (float*)(arena + 16384);    // aliases bufA (Z2 stage)
  float* redB = (float*)(arena + 24576);    // aliases bufB (Z1 stage)

  __shared__ int sh_lb;
  __shared__ u32 sh_Ts;
  __shared__ float sh_m, sh_Z1, sh_Z2;

  const int cs = (int)gcs[b];
  const u64* gc = gcand + (size_t)b * CAND;
  const int e_lo = (w << 7) + l;      // wave w owns elements [w*128, w*128+128)
  const int e_hi = e_lo + 64;
  const u64 SENT = 0xFFFFFFFFFFFFFFFFull;
  u64 k0 = (e_lo < cs) ? gc[e_lo] : SENT;
  u64 k1 = (e_hi < cs) ? gc[e_hi] : SENT;

  // bitonic sort over the smallest power-of-2 span P >= cs (uniform per block;
  // slots [cs,P) hold SENT so [0,cs) ends up ascending == JAX stable argsort).
  // strides <=32: shfl_xor; stride 64: register swap; strides >=128: LDS.
  int P = 64;
  while (P < cs) P <<= 1;
  for (int size = 2; size <= P; size <<= 1) {
    for (int s = size >> 1; s > 0; s >>= 1) {
      if (s >= 128) {
        cand[e_lo] = k0; cand[e_hi] = k1;
        __syncthreads();
        u64 p0 = cand[e_lo ^ s], p1 = cand[e_hi ^ s];
        {
          bool keepmin = (((e_lo & s) == 0) == ((e_lo & size) == 0));
          if (keepmin ? (p0 < k0) : (p0 > k0)) k0 = p0;
        }
        {
          bool keepmin = (((e_hi & s) == 0) == ((e_hi & size) == 0));
          if (keepmin ? (p1 < k1) : (p1 > k1)) k1 = p1;
        }
        __syncthreads();
      } else if (s == 64) {
        bool asc = ((e_lo & size) == 0);   // e_hi has same direction (size>=128)
        if ((k0 > k1) == asc) { u64 t = k0; k0 = k1; k1 = t; }
      } else {
        u64 p0 = shfl_xor_u64(k0, s);
        u64 p1 = shfl_xor_u64(k1, s);
        {
          bool keepmin = (((l & s) == 0) == ((e_lo & size) == 0));
          if (keepmin ? (p0 < k0) : (p0 > k0)) k0 = p0;
        }
        {
          bool keepmin = (((l & s) == 0) == ((e_hi & size) == 0));
          if (keepmin ? (p1 < k1) : (p1 > k1)) k1 = p1;
        }
      }
    }
  }
  cand[e_lo] = k0; cand[e_hi] = k1;
  __syncthreads();

  if (tid == 0) {
    int ti = cs - k; if (ti < 0) ti = 0;
    sh_Ts = (u32)(cand[ti] >> 32);             // k-th largest x (exact)
    sh_m  = s2f((u32)(cand[cs - 1] >> 32));    // row max
  }
  __syncthreads();
  const u32 Ts = sh_Ts;
  const float m = sh_m;

  // first survivor slot (values >= Ts form a contiguous suffix of [0,cs))
  for (int c = tid; c < cs; c += STHREADS) {
    u32 s = (u32)(cand[c] >> 32);
    if (s >= Ts && (c == 0 || (u32)(cand[c - 1] >> 32) < Ts)) sh_lb = c;
  }
  __syncthreads();
  const int lb = sh_lb;

  // e = exp(x - m); exact 0 for masked / pad
  for (int c = tid; c < CAND; c += STHREADS) {
    float e = 0.0f;
    if (c < cs) {
      u32 s = (u32)(cand[c] >> 32);
      if (s >= Ts) e = expf(s2f(s) - m);
    }
    bufA[c] = e;
  }
  __syncthreads();

  // Z1 tree reduce (association identical to round 3)
  {
    float local = bufA[tid] + bufA[tid + STHREADS];
    redB[tid] = local;
    __syncthreads();
    for (int s = STHREADS >> 1; s > 0; s >>= 1) {
      if (tid < s) redB[tid] += redB[tid + s];
      __syncthreads();
    }
    if (tid == 0) sh_Z1 = redB[0];
    __syncthreads();
  }

  // p = e/Z1
  const float Z1 = sh_Z1;
  for (int c = tid; c < CAND; c += STHREADS) bufA[c] = bufA[c] / Z1;
  __syncthreads();

  // exact sequential cumsum, wave-parallelized: lane l of wave 0 computes
  // carry + v0 + ... + vl in strict left-to-right order (skipped adds are
  // exact +0.0f) -> bit-identical to a single-thread sequential cumsum.
  // Broadcast of lane j's value uses v_readlane (constant j, fully unrolled):
  // VALU op into SGPR, no ds_bpermute / lgkmcnt dependency in the add chain.
  if (w == 0) {
    float carry = 0.0f;
    for (int base = lb; base < cs; base += 64) {
      int c = base + l;
      float v = (c < cs) ? bufA[c] : 0.0f;
      u32 vb = __float_as_uint(v);
      float acc = carry;
#pragma unroll
      for (int j = 0; j < 64; ++j) {
        float t = __uint_as_float(__builtin_amdgcn_readlane(vb, j));
        acc += (l >= j) ? t : 0.0f;
      }
      if (c < cs) bufB[c] = acc;
      carry = __uint_as_float(__builtin_amdgcn_readlane(__float_as_uint(acc), 63));
    }
  }
  __syncthreads();

  // top-p keep flags: drop iff cumsum <= 1-p, never drop last sorted pos
  for (int c = tid; c < CAND; c += STHREADS) {
    unsigned char kf = 0;
    if (c < cs) {
      u32 s = (u32)(cand[c] >> 32);
      if (s >= Ts && (c == cs - 1 || bufB[c] > one_minus_p)) kf = 1;
    }
    keepf[c] = kf;
  }
  __syncthreads();

  // Z2 tree reduce (association identical to round 3)
  {
    float local = 0.0f;
    for (int c = tid; c < CAND; c += STHREADS) {
      if (keepf[c]) {
        u32 s = (u32)(cand[c] >> 32);
        local += expf(s2f(s) - m);
      }
    }
    redA[tid] = local;
    __syncthreads();
    for (int s = STHREADS >> 1; s > 0; s >>= 1) {
      if (tid < s) redA[tid] += redA[tid + s];
      __syncthreads();
    }
    if (tid == 0) sh_Z2 = redA[0];
    __syncthreads();
  }

  // min_p: remove iff (e/Z2) < min_p * (1/Z2)
  {
    const float Z2 = sh_Z2;
    const float rhs = minp * (1.0f / Z2);
    for (int c = tid; c < CAND; c += STHREADS) {
      if (keepf[c]) {
        u32 s = (u32)(cand[c] >> 32);
        float p2 = expf(s2f(s) - m) / Z2;
        if (p2 < rhs) keepf[c] = 0;
      }
    }
  }
  __syncthreads();

  // gumbel-max (JAX categorical), first-index tie-break
  {
    const float TINY = 1.17549435082228750797e-38f;
    u64 best = 0ull;
    for (int c = lb + tid; c < cs; c += STHREADS) {
      if (!keepf[c]) continue;
      u32 s = (u32)(cand[c] >> 32);
      u32 idx = (u32)(cand[c] & 0xFFFFFFFFull);
      float x = s2f(s);
      u32 bits = threefry_bits((u32)b * (u32)V + idx);
      float f = __uint_as_float((bits >> 9) | 0x3f800000u) - 1.0f;
      float u = fmaxf(TINY, f * 1.0f + TINY);
      float g = -logf(-logf(u));
      float sc = g + x;
      u64 key = ((u64)f2s(sc) << 32) | (u64)(0xFFFFFFFFu - idx);
      if (key > best) best = key;
    }
    red64[tid] = best;
    __syncthreads();
    for (int s = STHREADS >> 1; s > 0; s >>= 1) {
      if (tid < s) { u64 o = red64[tid + s]; if (o > red64[tid]) red64[tid] = o; }
      __syncthreads();
    }
    if (tid == 0) out[b] = (int)(0xFFFFFFFFu - (u32)(red64[0] & 0xFFFFFFFFull));
  }
}

extern "C" void kernel_launch(void* const* d_in, const int* in_sizes, int n_in,
                              void* d_out, int out_size, void* d_ws, size_t ws_size,
                              hipStream_t stream) {
  const float* logits = (const float*)d_in[0];
  const float* temps  = (const float*)d_in[1];
  const float* minps  = (const float*)d_in[2];
  const float* topps  = (const float*)d_in[3];
  const int*   topks  = (const int*)d_in[4];
  const int B = in_sizes[1];
  const int V = in_sizes[0] / B;
  (void)n_in; (void)out_size; (void)ws_size;

  // scratch: ghist [B*HBINS] | done [B] | gcount [B] | gcs [B] | gthr [B] | gcand [B*CAND u64]
  u32* ghist  = (u32*)d_ws;
  u32* done   = ghist + (size_t)B * HBINS;
  u32* gcount = done + B;
  u32* gcs    = gcount + B;
  u32* gthr   = gcs + B;
  u64* gcand  = (u64*)(gthr + B);   // byte offset 4*B*(HBINS+4): 8-aligned for even B

  const int slice_len = (((V + NSLICES - 1) / NSLICES) + 3) & ~3;

  // zero ghist + done in one stream-ordered DMA (graph-capture safe)
  (void)hipMemsetAsync(ghist, 0, ((size_t)B * HBINS + B) * sizeof(u32), stream);
  histsel_kernel<<<dim3(B * NSLICES), dim3(HTHREADS), 0, stream>>>(
      logits, ghist, done, topks, gthr, gcs, gcount, V, slice_len);
  collect_kernel<<<dim3(B * NSLICES), dim3(CTHREADS), 0, stream>>>(
      logits, temps, gthr, gcount, gcand, V, slice_len);
  Sampler_73529840107542_kernel<<<dim3(B), dim3(STHREADS), 0, stream>>>(
      minps, topps, topks, gcs, gcand, (int*)d_out, V);
}

// Round 9
// 169.283 us; speedup vs baseline: 1.4117x; 1.4117x over previous
//
#include <hip/hip_runtime.h>
#include <stdint.h>

#define HBINS 8192
#define HSHIFT 19
#define CAND 2048
#define NSLICES 16
#define RTHREADS 1024
#define CTHREADS 256
#define STHREADS 1024

typedef unsigned int u32;
typedef unsigned long long u64;

// order-preserving float->uint map (ascending uint == ascending float)
__device__ __forceinline__ u32 f2s(float f) {
  u32 b = __float_as_uint(f);
  return b ^ ((b & 0x80000000u) ? 0xFFFFFFFFu : 0x80000000u);
}
__device__ __forceinline__ float s2f(u32 s) {
  u32 b = (s & 0x80000000u) ? (s ^ 0x80000000u) : ~s;
  return __uint_as_float(b);
}
__device__ __forceinline__ u32 rotl32(u32 x, int r) { return (x << r) | (x >> (32 - r)); }

__device__ __forceinline__ u64 shfl_xor_u64(u64 v, int mask) {
  int lo = __shfl_xor((int)(u32)v, mask, 64);
  int hi = __shfl_xor((int)(u32)(v >> 32), mask, 64);
  return ((u64)(u32)hi << 32) | (u32)lo;
}

// JAX threefry2x32, partitionable counter mode, key = jax.random.key(42) -> (0,42).
__device__ __forceinline__ u32 threefry_bits(u32 ctr) {
  const u32 ks0 = 0u, ks1 = 42u, ks2 = 0x1BD11BDAu ^ 0u ^ 42u;
  u32 x0 = ks0;
  u32 x1 = ctr + ks1;
#define TFR(r) { x0 += x1; x1 = rotl32(x1, (r)); x1 ^= x0; }
  TFR(13) TFR(15) TFR(26) TFR(6)   x0 += ks1; x1 += ks2 + 1u;
  TFR(17) TFR(29) TFR(16) TFR(24)  x0 += ks2; x1 += ks0 + 2u;
  TFR(13) TFR(15) TFR(26) TFR(6)   x0 += ks0; x1 += ks1 + 3u;
  TFR(17) TFR(29) TFR(16) TFR(24)  x0 += ks1; x1 += ks2 + 4u;
  TFR(13) TFR(15) TFR(26) TFR(6)   x0 += ks2; x1 += ks0 + 5u;
#undef TFR
  return x0 ^ x1;
}

// ---------------- per-row histogram + inline select (one block per row) -------
// The whole row's 8192-bin histogram lives in THIS block's LDS: two parity-
// split u32 copies (hp[2b+ (tid&1)]) to halve same-word atomic trains.
// No global hist array, no cross-block merge atomics, no fences, no memset.
// Select = suffix-scan over 1024 partials (8 bins each), same boundary logic
// as the round-8 hardware-verified select.
__global__ __launch_bounds__(RTHREADS)
void rowhist_kernel(const float* __restrict__ logits,
                    const int* __restrict__ topks,
                    u32* __restrict__ gthr, u32* __restrict__ gcs,
                    u32* __restrict__ gcount, int V) {
  const int row = blockIdx.x;
  const int tid = threadIdx.x;
  __shared__ u32 hp[2 * HBINS];     // 64 KB: hp[2b+c] = copy c of bin b
  __shared__ u32 part[RTHREADS];    // 4 KB suffix partials (8 bins each)
  __shared__ int sh_pstar;

  for (int i = tid; i < 2 * HBINS; i += RTHREADS) hp[i] = 0u;
  __syncthreads();

  const float* src = logits + (size_t)row * (size_t)V;
  const u32 c = (u32)(tid & 1);
  const int n4 = V >> 2;
  const float4* p4 = (const float4*)src;
  for (int i = tid; i < n4; i += RTHREADS) {
    float4 w = p4[i];
    atomicAdd(&hp[((f2s(w.x) >> HSHIFT) << 1) | c], 1u);
    atomicAdd(&hp[((f2s(w.y) >> HSHIFT) << 1) | c], 1u);
    atomicAdd(&hp[((f2s(w.z) >> HSHIFT) << 1) | c], 1u);
    atomicAdd(&hp[((f2s(w.w) >> HSHIFT) << 1) | c], 1u);
  }
  for (int i = (n4 << 2) + tid; i < V; i += RTHREADS)
    atomicAdd(&hp[((f2s(src[i]) >> HSHIFT) << 1) | c], 1u);
  __syncthreads();

  // part[t] = count of bins [t*8, t*8+8) = sum of hp[t*16 .. t*16+16)
  {
    u32 s = 0;
#pragma unroll
    for (int j = 0; j < 16; ++j) s += hp[tid * 16 + j];
    part[tid] = s;
  }
  __syncthreads();
  // Hillis-Steele suffix scan: part[t] = sum_{q>=t} part[q]  (part[0] == V)
  for (int st = 1; st < RTHREADS; st <<= 1) {
    u32 v = (tid + st < RTHREADS) ? part[tid + st] : 0u;
    __syncthreads();
    part[tid] += v;
    __syncthreads();
  }

  int k = topks[row];
  if (k < 1) k = 1;
  if (k > V) k = V;
  const u32 ku = (u32)k;

  // pstar = max t with part[t] >= ku (part non-increasing; part[0]=V>=ku)
  if (part[tid] >= ku && (tid == RTHREADS - 1 || part[tid + 1] < ku))
    sh_pstar = tid;
  __syncthreads();
  const int pstar = sh_pstar;
  const u32 tail = (pstar < RTHREADS - 1) ? part[pstar + 1] : 0u;
  if (tid < 8) {
    // bin bstar = pstar*8 + tid; cnt(b) = hp[2b] + hp[2b+1]
    u32 sb = tail;                         // suffix count from bin pstar*8+tid
    for (int j = 7; j >= tid; --j) sb += hp[(pstar * 8 + j) * 2] + hp[(pstar * 8 + j) * 2 + 1];
    u32 own = hp[(pstar * 8 + tid) * 2] + hp[(pstar * 8 + tid) * 2 + 1];
    if (sb >= ku && (tid == 7 || sb - own < ku)) {
      gthr[row] = (u32)(pstar * 8 + tid) << HSHIFT;
      gcs[row] = (sb < (u32)CAND) ? sb : (u32)CAND;
      gcount[row] = 0u;
    }
  }
}

// ---------------- per-slice collect (full machine, no hist traffic) -----------
__global__ __launch_bounds__(CTHREADS)
void collect_kernel(const float* __restrict__ logits,
                    const float* __restrict__ temps,
                    const u32* __restrict__ gthr,
                    u32* __restrict__ gcount,
                    u64* __restrict__ gcand, int V, int slice_len) {
  const int row = blockIdx.x / NSLICES;
  const int sl  = blockIdx.x % NSLICES;
  const int tid = threadIdx.x;

  __shared__ u64 stage[CAND];
  __shared__ int sh_cnt, sh_base;
  if (tid == 0) sh_cnt = 0;
  __syncthreads();

  const u32 thr = gthr[row];
  const float t = temps[row];
  int rem = V - sl * slice_len;
  if (rem > slice_len) rem = slice_len;
  if (rem < 0) rem = 0;
  const float* src = logits + (size_t)row * (size_t)V + (size_t)sl * slice_len;
  const u32 ibase = (u32)(sl * slice_len);
  const int n4 = rem >> 2;
  const float4* p4 = (const float4*)src;
  for (int i = tid; i < n4; i += CTHREADS) {
    float4 w = p4[i];
    if (f2s(w.x) >= thr) { int pos = atomicAdd(&sh_cnt, 1); if (pos < CAND) stage[pos] = ((u64)f2s(w.x / t) << 32) | (ibase + 4u * i + 0u); }
    if (f2s(w.y) >= thr) { int pos = atomicAdd(&sh_cnt, 1); if (pos < CAND) stage[pos] = ((u64)f2s(w.y / t) << 32) | (ibase + 4u * i + 1u); }
    if (f2s(w.z) >= thr) { int pos = atomicAdd(&sh_cnt, 1); if (pos < CAND) stage[pos] = ((u64)f2s(w.z / t) << 32) | (ibase + 4u * i + 2u); }
    if (f2s(w.w) >= thr) { int pos = atomicAdd(&sh_cnt, 1); if (pos < CAND) stage[pos] = ((u64)f2s(w.w / t) << 32) | (ibase + 4u * i + 3u); }
  }
  for (int i = (n4 << 2) + tid; i < rem; i += CTHREADS) {
    float l = src[i];
    if (f2s(l) >= thr) { int pos = atomicAdd(&sh_cnt, 1); if (pos < CAND) stage[pos] = ((u64)f2s(l / t) << 32) | (ibase + (u32)i); }
  }
  __syncthreads();
  int n = sh_cnt;
  if (n > CAND) n = CAND;
  if (tid == 0) sh_base = (int)atomicAdd(&gcount[row], (u32)n);
  __syncthreads();
  const int base = sh_base;
  u64* gc = gcand + (size_t)row * CAND;
  for (int i = tid; i < n; i += CTHREADS) {
    int dst = base + i;
    if (dst < CAND) gc[dst] = stage[i];
  }
}

// ---------------- per-row: hybrid reg/LDS sort + softmax chain + gumbel -------
__global__ __launch_bounds__(STHREADS)
void Sampler_73529840107542_kernel(const float* __restrict__ minps,
                                   const float* __restrict__ topps,
                                   const int* __restrict__ topks,
                                   const u32* __restrict__ gcs,
                                   const u64* __restrict__ gcand,
                                   int* __restrict__ out, int V) {
  const int b = blockIdx.x;
  const int tid = threadIdx.x;
  const int w = tid >> 6;
  const int l = tid & 63;
  const float one_minus_p = 1.0f - topps[b];
  const float minp = minps[b];
  int k = topks[b];
  if (k < 1) k = 1;
  if (k > V) k = V;

  __shared__ __align__(16) unsigned char arena[34816];
  u64* cand   = (u64*)(arena);              // [0,16384)
  float* bufA = (float*)(arena + 16384);    // [16384,24576) e / p
  float* bufB = (float*)(arena + 24576);    // [24576,32768) cumsum
  unsigned char* keepf = arena + 32768;     // [32768,34816)
  u64* red64  = (u64*)(arena + 16384);      // aliases bufA (argmax stage)
  float* redA = (float*)(arena + 16384);    // aliases bufA (Z2 stage)
  float* redB = (float*)(arena + 24576);    // aliases bufB (Z1 stage)

  __shared__ int sh_lb;
  __shared__ u32 sh_Ts;
  __shared__ float sh_m, sh_Z1, sh_Z2;

  const int cs = (int)gcs[b];
  const u64* gc = gcand + (size_t)b * CAND;
  const int e_lo = (w << 7) + l;      // wave w owns elements [w*128, w*128+128)
  const int e_hi = e_lo + 64;
  const u64 SENT = 0xFFFFFFFFFFFFFFFFull;
  u64 k0 = (e_lo < cs) ? gc[e_lo] : SENT;
  u64 k1 = (e_hi < cs) ? gc[e_hi] : SENT;

  // bitonic sort over the smallest power-of-2 span P >= cs (uniform per block;
  // slots [cs,P) hold SENT so [0,cs) ends up ascending == JAX stable argsort).
  // strides <=32: shfl_xor; stride 64: register swap; strides >=128: LDS.
  int P = 64;
  while (P < cs) P <<= 1;
  for (int size = 2; size <= P; size <<= 1) {
    for (int s = size >> 1; s > 0; s >>= 1) {
      if (s >= 128) {
        cand[e_lo] = k0; cand[e_hi] = k1;
        __syncthreads();
        u64 p0 = cand[e_lo ^ s], p1 = cand[e_hi ^ s];
        {
          bool keepmin = (((e_lo & s) == 0) == ((e_lo & size) == 0));
          if (keepmin ? (p0 < k0) : (p0 > k0)) k0 = p0;
        }
        {
          bool keepmin = (((e_hi & s) == 0) == ((e_hi & size) == 0));
          if (keepmin ? (p1 < k1) : (p1 > k1)) k1 = p1;
        }
        __syncthreads();
      } else if (s == 64) {
        bool asc = ((e_lo & size) == 0);   // e_hi has same direction (size>=128)
        if ((k0 > k1) == asc) { u64 t = k0; k0 = k1; k1 = t; }
      } else {
        u64 p0 = shfl_xor_u64(k0, s);
        u64 p1 = shfl_xor_u64(k1, s);
        {
          bool keepmin = (((l & s) == 0) == ((e_lo & size) == 0));
          if (keepmin ? (p0 < k0) : (p0 > k0)) k0 = p0;
        }
        {
          bool keepmin = (((l & s) == 0) == ((e_hi & size) == 0));
          if (keepmin ? (p1 < k1) : (p1 > k1)) k1 = p1;
        }
      }
    }
  }
  cand[e_lo] = k0; cand[e_hi] = k1;
  __syncthreads();

  if (tid == 0) {
    int ti = cs - k; if (ti < 0) ti = 0;
    sh_Ts = (u32)(cand[ti] >> 32);             // k-th largest x (exact)
    sh_m  = s2f((u32)(cand[cs - 1] >> 32));    // row max
  }
  __syncthreads();
  const u32 Ts = sh_Ts;
  const float m = sh_m;

  // first survivor slot (values >= Ts form a contiguous suffix of [0,cs))
  for (int c = tid; c < cs; c += STHREADS) {
    u32 s = (u32)(cand[c] >> 32);
    if (s >= Ts && (c == 0 || (u32)(cand[c - 1] >> 32) < Ts)) sh_lb = c;
  }
  __syncthreads();
  const int lb = sh_lb;

  // e = exp(x - m); exact 0 for masked / pad
  for (int c = tid; c < CAND; c += STHREADS) {
    float e = 0.0f;
    if (c < cs) {
      u32 s = (u32)(cand[c] >> 32);
      if (s >= Ts) e = expf(s2f(s) - m);
    }
    bufA[c] = e;
  }
  __syncthreads();

  // Z1 tree reduce (association identical to round 3)
  {
    float local = bufA[tid] + bufA[tid + STHREADS];
    redB[tid] = local;
    __syncthreads();
    for (int s = STHREADS >> 1; s > 0; s >>= 1) {
      if (tid < s) redB[tid] += redB[tid + s];
      __syncthreads();
    }
    if (tid == 0) sh_Z1 = redB[0];
    __syncthreads();
  }

  // p = e/Z1
  const float Z1 = sh_Z1;
  for (int c = tid; c < CAND; c += STHREADS) bufA[c] = bufA[c] / Z1;
  __syncthreads();

  // exact sequential cumsum, wave-parallelized: lane l of wave 0 computes
  // carry + v0 + ... + vl in strict left-to-right order (skipped adds are
  // exact +0.0f) -> bit-identical to a single-thread sequential cumsum.
  // Broadcast of lane j's value uses v_readlane (constant j, fully unrolled):
  // VALU op into SGPR, no ds_bpermute / lgkmcnt dependency in the add chain.
  if (w == 0) {
    float carry = 0.0f;
    for (int base = lb; base < cs; base += 64) {
      int c = base + l;
      float v = (c < cs) ? bufA[c] : 0.0f;
      u32 vb = __float_as_uint(v);
      float acc = carry;
#pragma unroll
      for (int j = 0; j < 64; ++j) {
        float t = __uint_as_float(__builtin_amdgcn_readlane(vb, j));
        acc += (l >= j) ? t : 0.0f;
      }
      if (c < cs) bufB[c] = acc;
      carry = __uint_as_float(__builtin_amdgcn_readlane(__float_as_uint(acc), 63));
    }
  }
  __syncthreads();

  // top-p keep flags: drop iff cumsum <= 1-p, never drop last sorted pos
  for (int c = tid; c < CAND; c += STHREADS) {
    unsigned char kf = 0;
    if (c < cs) {
      u32 s = (u32)(cand[c] >> 32);
      if (s >= Ts && (c == cs - 1 || bufB[c] > one_minus_p)) kf = 1;
    }
    keepf[c] = kf;
  }
  __syncthreads();

  // Z2 tree reduce (association identical to round 3)
  {
    float local = 0.0f;
    for (int c = tid; c < CAND; c += STHREADS) {
      if (keepf[c]) {
        u32 s = (u32)(cand[c] >> 32);
        local += expf(s2f(s) - m);
      }
    }
    redA[tid] = local;
    __syncthreads();
    for (int s = STHREADS >> 1; s > 0; s >>= 1) {
      if (tid < s) redA[tid] += redA[tid + s];
      __syncthreads();
    }
    if (tid == 0) sh_Z2 = redA[0];
    __syncthreads();
  }

  // min_p: remove iff (e/Z2) < min_p * (1/Z2)
  {
    const float Z2 = sh_Z2;
    const float rhs = minp * (1.0f / Z2);
    for (int c = tid; c < CAND; c += STHREADS) {
      if (keepf[c]) {
        u32 s = (u32)(cand[c] >> 32);
        float p2 = expf(s2f(s) - m) / Z2;
        if (p2 < rhs) keepf[c] = 0;
      }
    }
  }
  __syncthreads();

  // gumbel-max (JAX categorical), first-index tie-break
  {
    const float TINY = 1.17549435082228750797e-38f;
    u64 best = 0ull;
    for (int c = lb + tid; c < cs; c += STHREADS) {
      if (!keepf[c]) continue;
      u32 s = (u32)(cand[c] >> 32);
      u32 idx = (u32)(cand[c] & 0xFFFFFFFFull);
      float x = s2f(s);
      u32 bits = threefry_bits((u32)b * (u32)V + idx);
      float f = __uint_as_float((bits >> 9) | 0x3f800000u) - 1.0f;
      float u = fmaxf(TINY, f * 1.0f + TINY);
      float g = -logf(-logf(u));
      float sc = g + x;
      u64 key = ((u64)f2s(sc) << 32) | (u64)(0xFFFFFFFFu - idx);
      if (key > best) best = key;
    }
    red64[tid] = best;
    __syncthreads();
    for (int s = STHREADS >> 1; s > 0; s >>= 1) {
      if (tid < s) { u64 o = red64[tid + s]; if (o > red64[tid]) red64[tid] = o; }
      __syncthreads();
    }
    if (tid == 0) out[b] = (int)(0xFFFFFFFFu - (u32)(red64[0] & 0xFFFFFFFFull));
  }
}

extern "C" void kernel_launch(void* const* d_in, const int* in_sizes, int n_in,
                              void* d_out, int out_size, void* d_ws, size_t ws_size,
                              hipStream_t stream) {
  const float* logits = (const float*)d_in[0];
  const float* temps  = (const float*)d_in[1];
  const float* minps  = (const float*)d_in[2];
  const float* topps  = (const float*)d_in[3];
  const int*   topks  = (const int*)d_in[4];
  const int B = in_sizes[1];
  const int V = in_sizes[0] / B;
  (void)n_in; (void)out_size; (void)ws_size;

  // scratch: gcount [B] | gcs [B] | gthr [B] | gcand [B*CAND u64]
  u32* gcount = (u32*)d_ws;
  u32* gcs    = gcount + B;
  u32* gthr   = gcs + B;
  u64* gcand  = (u64*)(gthr + B);   // byte offset 12*B: 8-aligned for even B

  const int slice_len = (((V + NSLICES - 1) / NSLICES) + 3) & ~3;

  rowhist_kernel<<<dim3(B), dim3(RTHREADS), 0, stream>>>(
      logits, topks, gthr, gcs, gcount, V);
  collect_kernel<<<dim3(B * NSLICES), dim3(CTHREADS), 0, stream>>>(
      logits, temps, gthr, gcount, gcand, V, slice_len);
  Sampler_73529840107542_kernel<<<dim3(B), dim3(STHREADS), 0, stream>>>(
      minps, topps, topks, gcs, gcand, (int*)d_out, V);
}

// Round 10
// 165.473 us; speedup vs baseline: 1.4442x; 1.0230x over previous
//
#include <hip/hip_runtime.h>
#include <stdint.h>

#define HBINS 8192
#define HSHIFT 19
#define CAND 2048
#define NSLICES 16
#define RTHREADS 1024
#define CTHREADS 256
#define STHREADS 1024

typedef unsigned int u32;
typedef unsigned long long u64;

// order-preserving float->uint map (ascending uint == ascending float)
__device__ __forceinline__ u32 f2s(float f) {
  u32 b = __float_as_uint(f);
  return b ^ ((b & 0x80000000u) ? 0xFFFFFFFFu : 0x80000000u);
}
__device__ __forceinline__ float s2f(u32 s) {
  u32 b = (s & 0x80000000u) ? (s ^ 0x80000000u) : ~s;
  return __uint_as_float(b);
}
__device__ __forceinline__ u32 rotl32(u32 x, int r) { return (x << r) | (x >> (32 - r)); }

__device__ __forceinline__ u64 shfl_xor_u64(u64 v, int mask) {
  int lo = __shfl_xor((int)(u32)v, mask, 64);
  int hi = __shfl_xor((int)(u32)(v >> 32), mask, 64);
  return ((u64)(u32)hi << 32) | (u32)lo;
}
__device__ __forceinline__ u64 shfl_down_u64(u64 v, int delta) {
  int lo = __shfl_down((int)(u32)v, delta, 64);
  int hi = __shfl_down((int)(u32)(v >> 32), delta, 64);
  return ((u64)(u32)hi << 32) | (u32)lo;
}

// JAX threefry2x32, partitionable counter mode, key = jax.random.key(42) -> (0,42).
__device__ __forceinline__ u32 threefry_bits(u32 ctr) {
  const u32 ks0 = 0u, ks1 = 42u, ks2 = 0x1BD11BDAu ^ 0u ^ 42u;
  u32 x0 = ks0;
  u32 x1 = ctr + ks1;
#define TFR(r) { x0 += x1; x1 = rotl32(x1, (r)); x1 ^= x0; }
  TFR(13) TFR(15) TFR(26) TFR(6)   x0 += ks1; x1 += ks2 + 1u;
  TFR(17) TFR(29) TFR(16) TFR(24)  x0 += ks2; x1 += ks0 + 2u;
  TFR(13) TFR(15) TFR(26) TFR(6)   x0 += ks0; x1 += ks1 + 3u;
  TFR(17) TFR(29) TFR(16) TFR(24)  x0 += ks1; x1 += ks2 + 4u;
  TFR(13) TFR(15) TFR(26) TFR(6)   x0 += ks2; x1 += ks0 + 5u;
#undef TFR
  return x0 ^ x1;
}

// ---------------- per-row histogram + inline select (one block per row) -------
// Unchanged from round 9 (measured-good: no fences, no global hist).
__global__ __launch_bounds__(RTHREADS)
void rowhist_kernel(const float* __restrict__ logits,
                    const int* __restrict__ topks,
                    u32* __restrict__ gthr, u32* __restrict__ gcs,
                    u32* __restrict__ gcount, int V) {
  const int row = blockIdx.x;
  const int tid = threadIdx.x;
  __shared__ u32 hp[2 * HBINS];     // 64 KB: hp[2b+c] = copy c of bin b
  __shared__ u32 part[RTHREADS];    // 4 KB suffix partials (8 bins each)
  __shared__ int sh_pstar;

  for (int i = tid; i < 2 * HBINS; i += RTHREADS) hp[i] = 0u;
  __syncthreads();

  const float* src = logits + (size_t)row * (size_t)V;
  const u32 c = (u32)(tid & 1);
  const int n4 = V >> 2;
  const float4* p4 = (const float4*)src;
  for (int i = tid; i < n4; i += RTHREADS) {
    float4 w = p4[i];
    atomicAdd(&hp[((f2s(w.x) >> HSHIFT) << 1) | c], 1u);
    atomicAdd(&hp[((f2s(w.y) >> HSHIFT) << 1) | c], 1u);
    atomicAdd(&hp[((f2s(w.z) >> HSHIFT) << 1) | c], 1u);
    atomicAdd(&hp[((f2s(w.w) >> HSHIFT) << 1) | c], 1u);
  }
  for (int i = (n4 << 2) + tid; i < V; i += RTHREADS)
    atomicAdd(&hp[((f2s(src[i]) >> HSHIFT) << 1) | c], 1u);
  __syncthreads();

  // part[t] = count of bins [t*8, t*8+8) = sum of hp[t*16 .. t*16+16)
  {
    u32 s = 0;
#pragma unroll
    for (int j = 0; j < 16; ++j) s += hp[tid * 16 + j];
    part[tid] = s;
  }
  __syncthreads();
  // Hillis-Steele suffix scan: part[t] = sum_{q>=t} part[q]  (part[0] == V)
  for (int st = 1; st < RTHREADS; st <<= 1) {
    u32 v = (tid + st < RTHREADS) ? part[tid + st] : 0u;
    __syncthreads();
    part[tid] += v;
    __syncthreads();
  }

  int k = topks[row];
  if (k < 1) k = 1;
  if (k > V) k = V;
  const u32 ku = (u32)k;

  // pstar = max t with part[t] >= ku (part non-increasing; part[0]=V>=ku)
  if (part[tid] >= ku && (tid == RTHREADS - 1 || part[tid + 1] < ku))
    sh_pstar = tid;
  __syncthreads();
  const int pstar = sh_pstar;
  const u32 tail = (pstar < RTHREADS - 1) ? part[pstar + 1] : 0u;
  if (tid < 8) {
    // bin bstar = pstar*8 + tid; cnt(b) = hp[2b] + hp[2b+1]
    u32 sb = tail;                         // suffix count from bin pstar*8+tid
    for (int j = 7; j >= tid; --j) sb += hp[(pstar * 8 + j) * 2] + hp[(pstar * 8 + j) * 2 + 1];
    u32 own = hp[(pstar * 8 + tid) * 2] + hp[(pstar * 8 + tid) * 2 + 1];
    if (sb >= ku && (tid == 7 || sb - own < ku)) {
      gthr[row] = (u32)(pstar * 8 + tid) << HSHIFT;
      gcs[row] = (sb < (u32)CAND) ? sb : (u32)CAND;
      gcount[row] = 0u;
    }
  }
}

// ---------------- per-slice collect (unchanged from round 9) ------------------
__global__ __launch_bounds__(CTHREADS)
void collect_kernel(const float* __restrict__ logits,
                    const float* __restrict__ temps,
                    const u32* __restrict__ gthr,
                    u32* __restrict__ gcount,
                    u64* __restrict__ gcand, int V, int slice_len) {
  const int row = blockIdx.x / NSLICES;
  const int sl  = blockIdx.x % NSLICES;
  const int tid = threadIdx.x;

  __shared__ u64 stage[CAND];
  __shared__ int sh_cnt, sh_base;
  if (tid == 0) sh_cnt = 0;
  __syncthreads();

  const u32 thr = gthr[row];
  const float t = temps[row];
  int rem = V - sl * slice_len;
  if (rem > slice_len) rem = slice_len;
  if (rem < 0) rem = 0;
  const float* src = logits + (size_t)row * (size_t)V + (size_t)sl * slice_len;
  const u32 ibase = (u32)(sl * slice_len);
  const int n4 = rem >> 2;
  const float4* p4 = (const float4*)src;
  for (int i = tid; i < n4; i += CTHREADS) {
    float4 w = p4[i];
    if (f2s(w.x) >= thr) { int pos = atomicAdd(&sh_cnt, 1); if (pos < CAND) stage[pos] = ((u64)f2s(w.x / t) << 32) | (ibase + 4u * i + 0u); }
    if (f2s(w.y) >= thr) { int pos = atomicAdd(&sh_cnt, 1); if (pos < CAND) stage[pos] = ((u64)f2s(w.y / t) << 32) | (ibase + 4u * i + 1u); }
    if (f2s(w.z) >= thr) { int pos = atomicAdd(&sh_cnt, 1); if (pos < CAND) stage[pos] = ((u64)f2s(w.z / t) << 32) | (ibase + 4u * i + 2u); }
    if (f2s(w.w) >= thr) { int pos = atomicAdd(&sh_cnt, 1); if (pos < CAND) stage[pos] = ((u64)f2s(w.w / t) << 32) | (ibase + 4u * i + 3u); }
  }
  for (int i = (n4 << 2) + tid; i < rem; i += CTHREADS) {
    float l = src[i];
    if (f2s(l) >= thr) { int pos = atomicAdd(&sh_cnt, 1); if (pos < CAND) stage[pos] = ((u64)f2s(l / t) << 32) | (ibase + (u32)i); }
  }
  __syncthreads();
  int n = sh_cnt;
  if (n > CAND) n = CAND;
  if (tid == 0) sh_base = (int)atomicAdd(&gcount[row], (u32)n);
  __syncthreads();
  const int base = sh_base;
  u64* gc = gcand + (size_t)row * CAND;
  for (int i = tid; i < n; i += CTHREADS) {
    int dst = base + i;
    if (dst < CAND) gc[dst] = stage[i];
  }
}

// ---------------- per-row sampler: fused phases, fewer barriers ---------------
// All FP associations are bit-identical to the round-9 kernel:
//  - exp fused into Z1 level 0 (same adds), /Z1 folded into cumsum loads,
//    keep-flags fused into Z2 accumulation (same thread, same c-order),
//  - tree tails (s<64) via wave-0 shfl_down: same halving-tree association.
__global__ __launch_bounds__(STHREADS)
void Sampler_73529840107542_kernel(const float* __restrict__ minps,
                                   const float* __restrict__ topps,
                                   const int* __restrict__ topks,
                                   const u32* __restrict__ gcs,
                                   const u64* __restrict__ gcand,
                                   int* __restrict__ out, int V) {
  const int b = blockIdx.x;
  const int tid = threadIdx.x;
  const int w = tid >> 6;
  const int l = tid & 63;
  const float one_minus_p = 1.0f - topps[b];
  const float minp = minps[b];
  int k = topks[b];
  if (k < 1) k = 1;
  if (k > V) k = V;

  __shared__ __align__(16) unsigned char arena[34816];
  u64* cand   = (u64*)(arena);              // [0,16384)
  float* bufA = (float*)(arena + 16384);    // [16384,24576) e
  float* bufB = (float*)(arena + 24576);    // [24576,32768) cumsum
  unsigned char* keepf = arena + 32768;     // [32768,34816)
  u64* red64  = (u64*)(arena + 16384);      // aliases bufA+bufB (argmax stage)
  float* redA = (float*)(arena + 16384);    // aliases bufA (Z2 stage)
  float* redB = (float*)(arena + 24576);    // aliases bufB (Z1 stage)

  __shared__ int sh_lb;
  __shared__ u32 sh_Ts;
  __shared__ float sh_m, sh_Z1, sh_Z2;

  const int cs = (int)gcs[b];
  const u64* gc = gcand + (size_t)b * CAND;
  const int e_lo = (w << 7) + l;      // wave w owns elements [w*128, w*128+128)
  const int e_hi = e_lo + 64;
  const u64 SENT = 0xFFFFFFFFFFFFFFFFull;
  u64 k0 = (e_lo < cs) ? gc[e_lo] : SENT;
  u64 k1 = (e_hi < cs) ? gc[e_hi] : SENT;

  // bitonic sort over the smallest power-of-2 span P >= cs (uniform per block;
  // slots [cs,P) hold SENT so [0,cs) ends up ascending == JAX stable argsort).
  // strides <=32: shfl_xor; stride 64: register swap; strides >=128: LDS.
  int P = 64;
  while (P < cs) P <<= 1;
  for (int size = 2; size <= P; size <<= 1) {
    for (int s = size >> 1; s > 0; s >>= 1) {
      if (s >= 128) {
        cand[e_lo] = k0; cand[e_hi] = k1;
        __syncthreads();
        u64 p0 = cand[e_lo ^ s], p1 = cand[e_hi ^ s];
        {
          bool keepmin = (((e_lo & s) == 0) == ((e_lo & size) == 0));
          if (keepmin ? (p0 < k0) : (p0 > k0)) k0 = p0;
        }
        {
          bool keepmin = (((e_hi & s) == 0) == ((e_hi & size) == 0));
          if (keepmin ? (p1 < k1) : (p1 > k1)) k1 = p1;
        }
        __syncthreads();
      } else if (s == 64) {
        bool asc = ((e_lo & size) == 0);   // e_hi has same direction (size>=128)
        if ((k0 > k1) == asc) { u64 t = k0; k0 = k1; k1 = t; }
      } else {
        u64 p0 = shfl_xor_u64(k0, s);
        u64 p1 = shfl_xor_u64(k1, s);
        {
          bool keepmin = (((l & s) == 0) == ((e_lo & size) == 0));
          if (keepmin ? (p0 < k0) : (p0 > k0)) k0 = p0;
        }
        {
          bool keepmin = (((l & s) == 0) == ((e_hi & size) == 0));
          if (keepmin ? (p1 < k1) : (p1 > k1)) k1 = p1;
        }
      }
    }
  }
  cand[e_lo] = k0; cand[e_hi] = k1;
  __syncthreads();

  if (tid == 0) {
    int ti = cs - k; if (ti < 0) ti = 0;
    sh_Ts = (u32)(cand[ti] >> 32);             // k-th largest x (exact)
    sh_m  = s2f((u32)(cand[cs - 1] >> 32));    // row max
  }
  __syncthreads();
  const u32 Ts = sh_Ts;
  const float m = sh_m;

  // first survivor slot (values >= Ts form a contiguous suffix of [0,cs))
  for (int c = tid; c < cs; c += STHREADS) {
    u32 s = (u32)(cand[c] >> 32);
    if (s >= Ts && (c == 0 || (u32)(cand[c - 1] >> 32) < Ts)) sh_lb = c;
  }
  __syncthreads();
  const int lb = sh_lb;

  // fused: e = exp(x - m) for c = tid and tid+1024, stored to bufA, and
  // Z1 tree level 0 (local = e0 + e1) -- identical adds to the old 2-pass form.
  {
    float e0 = 0.0f, e1 = 0.0f;
    const int c0 = tid, c1 = tid + STHREADS;
    if (c0 < cs) {
      u32 s = (u32)(cand[c0] >> 32);
      if (s >= Ts) e0 = expf(s2f(s) - m);
    }
    if (c1 < cs) {
      u32 s = (u32)(cand[c1] >> 32);
      if (s >= Ts) e1 = expf(s2f(s) - m);
    }
    bufA[c0] = e0;
    bufA[c1] = e1;
    redB[tid] = e0 + e1;
  }
  __syncthreads();
  for (int s = STHREADS >> 1; s >= 64; s >>= 1) {
    if (tid < s) redB[tid] += redB[tid + s];
    __syncthreads();
  }
  if (w == 0) {   // shfl_down tail == same halving-tree association
    float v = redB[l];
    v += __shfl_down(v, 32, 64);
    v += __shfl_down(v, 16, 64);
    v += __shfl_down(v, 8, 64);
    v += __shfl_down(v, 4, 64);
    v += __shfl_down(v, 2, 64);
    v += __shfl_down(v, 1, 64);
    if (l == 0) sh_Z1 = v;
  }
  __syncthreads();
  const float Z1 = sh_Z1;

  // exact sequential cumsum over p = e/Z1, wave-parallelized; division folded
  // into the load (same per-element op as the old separate p-pass).
  if (w == 0) {
    float carry = 0.0f;
    for (int base = lb; base < cs; base += 64) {
      int c = base + l;
      float v = (c < cs) ? bufA[c] / Z1 : 0.0f;
      u32 vb = __float_as_uint(v);
      float acc = carry;
#pragma unroll
      for (int j = 0; j < 64; ++j) {
        float t = __uint_as_float(__builtin_amdgcn_readlane(vb, j));
        acc += (l >= j) ? t : 0.0f;
      }
      if (c < cs) bufB[c] = acc;
      carry = __uint_as_float(__builtin_amdgcn_readlane(__float_as_uint(acc), 63));
    }
  }
  __syncthreads();

  // fused: top-p keep flags + Z2 accumulation (same thread, same c-order ->
  // identical add sequence to the old 2-pass form).
  {
    float local = 0.0f;
    for (int c = tid; c < CAND; c += STHREADS) {
      unsigned char kf = 0;
      if (c < cs) {
        u32 s = (u32)(cand[c] >> 32);
        if (s >= Ts && (c == cs - 1 || bufB[c] > one_minus_p)) kf = 1;
        if (kf) local += expf(s2f(s) - m);
      }
      keepf[c] = kf;
    }
    redA[tid] = local;
  }
  __syncthreads();
  for (int s = STHREADS >> 1; s >= 64; s >>= 1) {
    if (tid < s) redA[tid] += redA[tid + s];
    __syncthreads();
  }
  if (w == 0) {
    float v = redA[l];
    v += __shfl_down(v, 32, 64);
    v += __shfl_down(v, 16, 64);
    v += __shfl_down(v, 8, 64);
    v += __shfl_down(v, 4, 64);
    v += __shfl_down(v, 2, 64);
    v += __shfl_down(v, 1, 64);
    if (l == 0) sh_Z2 = v;
  }
  __syncthreads();

  // min_p: remove iff (e/Z2) < min_p * (1/Z2)   (own-c loop, no barrier inside)
  {
    const float Z2 = sh_Z2;
    const float rhs = minp * (1.0f / Z2);
    for (int c = tid; c < CAND; c += STHREADS) {
      if (keepf[c]) {
        u32 s = (u32)(cand[c] >> 32);
        float p2 = expf(s2f(s) - m) / Z2;
        if (p2 < rhs) keepf[c] = 0;
      }
    }
  }
  __syncthreads();

  // gumbel-max (JAX categorical), first-index tie-break; max tree is exact so
  // the shfl tail is safe.
  {
    const float TINY = 1.17549435082228750797e-38f;
    u64 best = 0ull;
    for (int c = lb + tid; c < cs; c += STHREADS) {
      if (!keepf[c]) continue;
      u32 s = (u32)(cand[c] >> 32);
      u32 idx = (u32)(cand[c] & 0xFFFFFFFFull);
      float x = s2f(s);
      u32 bits = threefry_bits((u32)b * (u32)V + idx);
      float f = __uint_as_float((bits >> 9) | 0x3f800000u) - 1.0f;
      float u = fmaxf(TINY, f * 1.0f + TINY);
      float g = -logf(-logf(u));
      float sc = g + x;
      u64 key = ((u64)f2s(sc) << 32) | (u64)(0xFFFFFFFFu - idx);
      if (key > best) best = key;
    }
    red64[tid] = best;
    __syncthreads();
    for (int s = STHREADS >> 1; s >= 64; s >>= 1) {
      if (tid < s) { u64 o = red64[tid + s]; if (o > red64[tid]) red64[tid] = o; }
      __syncthreads();
    }
    if (w == 0) {
      u64 v = red64[l];
#pragma unroll
      for (int d = 32; d >= 1; d >>= 1) {
        u64 o = shfl_down_u64(v, d);
        if (o > v) v = o;
      }
      if (l == 0) out[b] = (int)(0xFFFFFFFFu - (u32)(v & 0xFFFFFFFFull));
    }
  }
}

extern "C" void kernel_launch(void* const* d_in, const int* in_sizes, int n_in,
                              void* d_out, int out_size, void* d_ws, size_t ws_size,
                              hipStream_t stream) {
  const float* logits = (const float*)d_in[0];
  const float* temps  = (const float*)d_in[1];
  const float* minps  = (const float*)d_in[2];
  const float* topps  = (const float*)d_in[3];
  const int*   topks  = (const int*)d_in[4];
  const int B = in_sizes[1];
  const int V = in_sizes[0] / B;
  (void)n_in; (void)out_size; (void)ws_size;

  // scratch: gcount [B] | gcs [B] | gthr [B] | gcand [B*CAND u64]
  u32* gcount = (u32*)d_ws;
  u32* gcs    = gcount + B;
  u32* gthr   = gcs + B;
  u64* gcand  = (u64*)(gthr + B);   // byte offset 12*B: 8-aligned for even B

  const int slice_len = (((V + NSLICES - 1) / NSLICES) + 3) & ~3;

  rowhist_kernel<<<dim3(B), dim3(RTHREADS), 0, stream>>>(
      logits, topks, gthr, gcs, gcount, V);
  collect_kernel<<<dim3(B * NSLICES), dim3(CTHREADS), 0, stream>>>(
      logits, temps, gthr, gcount, gcand, V, slice_len);
  Sampler_73529840107542_kernel<<<dim3(B), dim3(STHREADS), 0, stream>>>(
      minps, topps, topks, gcs, gcand, (int*)d_out, V);
}

// Round 11
// 164.030 us; speedup vs baseline: 1.4570x; 1.0088x over previous
//
#include <hip/hip_runtime.h>
#include <stdint.h>

#define HBINS 8192
#define HSHIFT 19
#define CAND 2048
#define STHREADS 1024

typedef unsigned int u32;
typedef unsigned long long u64;

// order-preserving float->uint map (ascending uint == ascending float)
__device__ __forceinline__ u32 f2s(float f) {
  u32 b = __float_as_uint(f);
  return b ^ ((b & 0x80000000u) ? 0xFFFFFFFFu : 0x80000000u);
}
__device__ __forceinline__ float s2f(u32 s) {
  u32 b = (s & 0x80000000u) ? (s ^ 0x80000000u) : ~s;
  return __uint_as_float(b);
}
__device__ __forceinline__ u32 rotl32(u32 x, int r) { return (x << r) | (x >> (32 - r)); }

__device__ __forceinline__ u64 shfl_xor_u64(u64 v, int mask) {
  int lo = __shfl_xor((int)(u32)v, mask, 64);
  int hi = __shfl_xor((int)(u32)(v >> 32), mask, 64);
  return ((u64)(u32)hi << 32) | (u32)lo;
}
__device__ __forceinline__ u64 shfl_down_u64(u64 v, int delta) {
  int lo = __shfl_down((int)(u32)v, delta, 64);
  int hi = __shfl_down((int)(u32)(v >> 32), delta, 64);
  return ((u64)(u32)hi << 32) | (u32)lo;
}

// JAX threefry2x32, partitionable counter mode, key = jax.random.key(42) -> (0,42).
__device__ __forceinline__ u32 threefry_bits(u32 ctr) {
  const u32 ks0 = 0u, ks1 = 42u, ks2 = 0x1BD11BDAu ^ 0u ^ 42u;
  u32 x0 = ks0;
  u32 x1 = ctr + ks1;
#define TFR(r) { x0 += x1; x1 = rotl32(x1, (r)); x1 ^= x0; }
  TFR(13) TFR(15) TFR(26) TFR(6)   x0 += ks1; x1 += ks2 + 1u;
  TFR(17) TFR(29) TFR(16) TFR(24)  x0 += ks2; x1 += ks0 + 2u;
  TFR(13) TFR(15) TFR(26) TFR(6)   x0 += ks0; x1 += ks1 + 3u;
  TFR(17) TFR(29) TFR(16) TFR(24)  x0 += ks1; x1 += ks2 + 4u;
  TFR(13) TFR(15) TFR(26) TFR(6)   x0 += ks2; x1 += ks0 + 5u;
#undef TFR
  return x0 ^ x1;
}

// ---------------- fully fused per-row pipeline (one block per row) -----------
// hist -> select -> collect -> sort -> softmax chain -> gumbel, all row-local.
// No cross-block communication, no global scratch for candidates.
// LDS arena phase-aliasing:
//   phase 1-2: hp[16384 u32] (64 KB, 2-copy parity hist) + part[1024 u32] (4 KB)
//   phase 3+ : cand[2048 u64] (16 KB, aliases hp) + bufA/bufB/keepf (round-10
//              sampler layout, all within the first 34.8 KB of the arena)
// All FP associations identical to the round-10 kernel (absmax 0.0 verified).
__global__ __launch_bounds__(STHREADS)
void Sampler_73529840107542_kernel(const float* __restrict__ logits,
                                   const float* __restrict__ temps,
                                   const float* __restrict__ minps,
                                   const float* __restrict__ topps,
                                   const int* __restrict__ topks,
                                   int* __restrict__ out, int V) {
  const int row = blockIdx.x;
  const int tid = threadIdx.x;
  const int w = tid >> 6;
  const int l = tid & 63;

  __shared__ __align__(16) unsigned char arena[69632];   // 68 KB
  u32* hp     = (u32*)arena;                 // [0,65536)  phase 1-2
  u32* part   = (u32*)(arena + 65536);       // [65536,69632) phase 2
  u64* cand   = (u64*)arena;                 // [0,16384)  phase 3+
  float* bufA = (float*)(arena + 16384);     // e
  float* bufB = (float*)(arena + 24576);     // cumsum
  unsigned char* keepf = arena + 32768;
  u64* red64  = (u64*)(arena + 16384);       // argmax stage (aliases bufA)
  float* redA = (float*)(arena + 16384);     // Z2 stage
  float* redB = (float*)(arena + 24576);     // Z1 stage

  __shared__ int sh_pstar, sh_cnt, sh_lb, sh_cs;
  __shared__ u32 sh_thr, sh_Ts;
  __shared__ float sh_m, sh_Z1, sh_Z2;

  // ---------------- phase 1: 8192-bin raw-logit histogram ----------------
  for (int i = tid; i < 2 * HBINS; i += STHREADS) hp[i] = 0u;
  __syncthreads();
  const float* src = logits + (size_t)row * (size_t)V;
  const u32 pc = (u32)(tid & 1);             // parity copy to halve atomic trains
  const int n4 = V >> 2;
  const float4* p4 = (const float4*)src;
  for (int i = tid; i < n4; i += STHREADS) {
    float4 v = p4[i];
    atomicAdd(&hp[((f2s(v.x) >> HSHIFT) << 1) | pc], 1u);
    atomicAdd(&hp[((f2s(v.y) >> HSHIFT) << 1) | pc], 1u);
    atomicAdd(&hp[((f2s(v.z) >> HSHIFT) << 1) | pc], 1u);
    atomicAdd(&hp[((f2s(v.w) >> HSHIFT) << 1) | pc], 1u);
  }
  for (int i = (n4 << 2) + tid; i < V; i += STHREADS)
    atomicAdd(&hp[((f2s(src[i]) >> HSHIFT) << 1) | pc], 1u);
  __syncthreads();

  // ---------------- phase 2: top-k bin threshold (suffix-scan select) -----
  {
    u32 s = 0;
#pragma unroll
    for (int j = 0; j < 16; ++j) s += hp[tid * 16 + j];   // bins [tid*8, tid*8+8)
    part[tid] = s;
  }
  __syncthreads();
  for (int st = 1; st < STHREADS; st <<= 1) {             // suffix scan
    u32 v = (tid + st < STHREADS) ? part[tid + st] : 0u;
    __syncthreads();
    part[tid] += v;
    __syncthreads();
  }
  int k = topks[row];
  if (k < 1) k = 1;
  if (k > V) k = V;
  const u32 ku = (u32)k;
  if (part[tid] >= ku && (tid == STHREADS - 1 || part[tid + 1] < ku))
    sh_pstar = tid;
  __syncthreads();
  {
    const int pstar = sh_pstar;
    const u32 tail = (pstar < STHREADS - 1) ? part[pstar + 1] : 0u;
    if (tid < 8) {
      u32 sb = tail;                          // suffix count from bin pstar*8+tid
      for (int j = 7; j >= tid; --j) sb += hp[(pstar * 8 + j) * 2] + hp[(pstar * 8 + j) * 2 + 1];
      u32 own = hp[(pstar * 8 + tid) * 2] + hp[(pstar * 8 + tid) * 2 + 1];
      if (sb >= ku && (tid == 7 || sb - own < ku)) {
        sh_thr = (u32)(pstar * 8 + tid) << HSHIFT;
        sh_cs = (int)((sb < (u32)CAND) ? sb : (u32)CAND);
      }
    }
    if (tid == 0) sh_cnt = 0;
  }
  __syncthreads();

  // ---------------- phase 3: collect candidates into LDS cand ------------
  // (cand aliases hp; hp is dead. Arbitrary append order is fine: the sort
  //  key (val<<32)|idx is a total order, so the sorted result is unique.)
  const u32 thr = sh_thr;
  const float t = temps[row];
  for (int i = tid; i < n4; i += STHREADS) {
    float4 v = p4[i];
    if (f2s(v.x) >= thr) { int pos = atomicAdd(&sh_cnt, 1); if (pos < CAND) cand[pos] = ((u64)f2s(v.x / t) << 32) | (u32)(4 * i + 0); }
    if (f2s(v.y) >= thr) { int pos = atomicAdd(&sh_cnt, 1); if (pos < CAND) cand[pos] = ((u64)f2s(v.y / t) << 32) | (u32)(4 * i + 1); }
    if (f2s(v.z) >= thr) { int pos = atomicAdd(&sh_cnt, 1); if (pos < CAND) cand[pos] = ((u64)f2s(v.z / t) << 32) | (u32)(4 * i + 2); }
    if (f2s(v.w) >= thr) { int pos = atomicAdd(&sh_cnt, 1); if (pos < CAND) cand[pos] = ((u64)f2s(v.w / t) << 32) | (u32)(4 * i + 3); }
  }
  for (int i = (n4 << 2) + tid; i < V; i += STHREADS) {
    float x = src[i];
    if (f2s(x) >= thr) { int pos = atomicAdd(&sh_cnt, 1); if (pos < CAND) cand[pos] = ((u64)f2s(x / t) << 32) | (u32)i; }
  }
  __syncthreads();
  const int cs = sh_cs;

  // ---------------- phase 4: bitonic sort (round-10 code, LDS input) ------
  const float one_minus_p = 1.0f - topps[row];
  const float minp = minps[row];
  const int e_lo = (w << 7) + l;
  const int e_hi = e_lo + 64;
  const u64 SENT = 0xFFFFFFFFFFFFFFFFull;
  u64 k0 = (e_lo < cs) ? cand[e_lo] : SENT;
  u64 k1 = (e_hi < cs) ? cand[e_hi] : SENT;
  __syncthreads();   // all initial cand reads complete before sort overwrites

  int P = 64;
  while (P < cs) P <<= 1;
  for (int size = 2; size <= P; size <<= 1) {
    for (int s = size >> 1; s > 0; s >>= 1) {
      if (s >= 128) {
        cand[e_lo] = k0; cand[e_hi] = k1;
        __syncthreads();
        u64 p0 = cand[e_lo ^ s], p1 = cand[e_hi ^ s];
        {
          bool keepmin = (((e_lo & s) == 0) == ((e_lo & size) == 0));
          if (keepmin ? (p0 < k0) : (p0 > k0)) k0 = p0;
        }
        {
          bool keepmin = (((e_hi & s) == 0) == ((e_hi & size) == 0));
          if (keepmin ? (p1 < k1) : (p1 > k1)) k1 = p1;
        }
        __syncthreads();
      } else if (s == 64) {
        bool asc = ((e_lo & size) == 0);
        if ((k0 > k1) == asc) { u64 tt = k0; k0 = k1; k1 = tt; }
      } else {
        u64 p0 = shfl_xor_u64(k0, s);
        u64 p1 = shfl_xor_u64(k1, s);
        {
          bool keepmin = (((l & s) == 0) == ((e_lo & size) == 0));
          if (keepmin ? (p0 < k0) : (p0 > k0)) k0 = p0;
        }
        {
          bool keepmin = (((l & s) == 0) == ((e_hi & size) == 0));
          if (keepmin ? (p1 < k1) : (p1 > k1)) k1 = p1;
        }
      }
    }
  }
  cand[e_lo] = k0; cand[e_hi] = k1;
  __syncthreads();

  // ---------------- phase 5+: softmax chain (identical to round 10) -------
  if (tid == 0) {
    int ti = cs - k; if (ti < 0) ti = 0;
    sh_Ts = (u32)(cand[ti] >> 32);             // k-th largest x (exact)
    sh_m  = s2f((u32)(cand[cs - 1] >> 32));    // row max
  }
  __syncthreads();
  const u32 Ts = sh_Ts;
  const float m = sh_m;

  for (int c = tid; c < cs; c += STHREADS) {
    u32 s = (u32)(cand[c] >> 32);
    if (s >= Ts && (c == 0 || (u32)(cand[c - 1] >> 32) < Ts)) sh_lb = c;
  }
  __syncthreads();
  const int lb = sh_lb;

  // fused exp + Z1 level 0
  {
    float e0 = 0.0f, e1 = 0.0f;
    const int c0 = tid, c1 = tid + STHREADS;
    if (c0 < cs) {
      u32 s = (u32)(cand[c0] >> 32);
      if (s >= Ts) e0 = expf(s2f(s) - m);
    }
    if (c1 < cs) {
      u32 s = (u32)(cand[c1] >> 32);
      if (s >= Ts) e1 = expf(s2f(s) - m);
    }
    bufA[c0] = e0;
    bufA[c1] = e1;
    redB[tid] = e0 + e1;
  }
  __syncthreads();
  for (int s = STHREADS >> 1; s >= 64; s >>= 1) {
    if (tid < s) redB[tid] += redB[tid + s];
    __syncthreads();
  }
  if (w == 0) {
    float v = redB[l];
    v += __shfl_down(v, 32, 64);
    v += __shfl_down(v, 16, 64);
    v += __shfl_down(v, 8, 64);
    v += __shfl_down(v, 4, 64);
    v += __shfl_down(v, 2, 64);
    v += __shfl_down(v, 1, 64);
    if (l == 0) sh_Z1 = v;
  }
  __syncthreads();
  const float Z1 = sh_Z1;

  // exact sequential cumsum over p = e/Z1 (readlane broadcast, wave 0)
  if (w == 0) {
    float carry = 0.0f;
    for (int base = lb; base < cs; base += 64) {
      int c = base + l;
      float v = (c < cs) ? bufA[c] / Z1 : 0.0f;
      u32 vb = __float_as_uint(v);
      float acc = carry;
#pragma unroll
      for (int j = 0; j < 64; ++j) {
        float tt = __uint_as_float(__builtin_amdgcn_readlane(vb, j));
        acc += (l >= j) ? tt : 0.0f;
      }
      if (c < cs) bufB[c] = acc;
      carry = __uint_as_float(__builtin_amdgcn_readlane(__float_as_uint(acc), 63));
    }
  }
  __syncthreads();

  // fused top-p keep flags + Z2 accumulation
  {
    float local = 0.0f;
    for (int c = tid; c < CAND; c += STHREADS) {
      unsigned char kf = 0;
      if (c < cs) {
        u32 s = (u32)(cand[c] >> 32);
        if (s >= Ts && (c == cs - 1 || bufB[c] > one_minus_p)) kf = 1;
        if (kf) local += expf(s2f(s) - m);
      }
      keepf[c] = kf;
    }
    redA[tid] = local;
  }
  __syncthreads();
  for (int s = STHREADS >> 1; s >= 64; s >>= 1) {
    if (tid < s) redA[tid] += redA[tid + s];
    __syncthreads();
  }
  if (w == 0) {
    float v = redA[l];
    v += __shfl_down(v, 32, 64);
    v += __shfl_down(v, 16, 64);
    v += __shfl_down(v, 8, 64);
    v += __shfl_down(v, 4, 64);
    v += __shfl_down(v, 2, 64);
    v += __shfl_down(v, 1, 64);
    if (l == 0) sh_Z2 = v;
  }
  __syncthreads();

  // min_p
  {
    const float Z2 = sh_Z2;
    const float rhs = minp * (1.0f / Z2);
    for (int c = tid; c < CAND; c += STHREADS) {
      if (keepf[c]) {
        u32 s = (u32)(cand[c] >> 32);
        float p2 = expf(s2f(s) - m) / Z2;
        if (p2 < rhs) keepf[c] = 0;
      }
    }
  }
  __syncthreads();

  // gumbel-max (JAX categorical), first-index tie-break
  {
    const float TINY = 1.17549435082228750797e-38f;
    u64 best = 0ull;
    for (int c = lb + tid; c < cs; c += STHREADS) {
      if (!keepf[c]) continue;
      u32 s = (u32)(cand[c] >> 32);
      u32 idx = (u32)(cand[c] & 0xFFFFFFFFull);
      float x = s2f(s);
      u32 bits = threefry_bits((u32)row * (u32)V + idx);
      float f = __uint_as_float((bits >> 9) | 0x3f800000u) - 1.0f;
      float u = fmaxf(TINY, f * 1.0f + TINY);
      float g = -logf(-logf(u));
      float sc = g + x;
      u64 key = ((u64)f2s(sc) << 32) | (u64)(0xFFFFFFFFu - idx);
      if (key > best) best = key;
    }
    red64[tid] = best;
    __syncthreads();
    for (int s = STHREADS >> 1; s >= 64; s >>= 1) {
      if (tid < s) { u64 o = red64[tid + s]; if (o > red64[tid]) red64[tid] = o; }
      __syncthreads();
    }
    if (w == 0) {
      u64 v = red64[l];
#pragma unroll
      for (int d = 32; d >= 1; d >>= 1) {
        u64 o = shfl_down_u64(v, d);
        if (o > v) v = o;
      }
      if (l == 0) out[row] = (int)(0xFFFFFFFFu - (u32)(v & 0xFFFFFFFFull));
    }
  }
}

extern "C" void kernel_launch(void* const* d_in, const int* in_sizes, int n_in,
                              void* d_out, int out_size, void* d_ws, size_t ws_size,
                              hipStream_t stream) {
  const float* logits = (const float*)d_in[0];
  const float* temps  = (const float*)d_in[1];
  const float* minps  = (const float*)d_in[2];
  const float* topps  = (const float*)d_in[3];
  const int*   topks  = (const int*)d_in[4];
  const int B = in_sizes[1];
  const int V = in_sizes[0] / B;
  (void)n_in; (void)out_size; (void)d_ws; (void)ws_size;

  Sampler_73529840107542_kernel<<<dim3(B), dim3(STHREADS), 0, stream>>>(
      logits, temps, minps, topps, topks, (int*)d_out, V);
}